// Round 8
// baseline (219.850 us; speedup 1.0000x reference)
//
#include <hip/hip_runtime.h>
#include <hip/hip_fp16.h>
#include <cstdint>
#include <cstddef>

// ---------------------------------------------------------------------------
// 2-layer GCN: h1 = x@W1; s = softmax(A_norm@h1 + b1); out = A_norm@(s@W2) + b2
// CSR build: wg-private two-level counting sort (zero global atomics).
// GEMMs: fp16 MFMA (v_mfma_f32_16x16x32_f16), zero LDS, pre-packed W.
// Aggregation: 8-lane groups, work-stealing node queue per block (one atomic
// per GROUP, lane0 + shfl broadcast), fp16 intermediates, unrolled gathers.
// ---------------------------------------------------------------------------

#define BSHIFT 8              // 256 nodes per bucket
#define NBPAD 512             // padded bucket count (NB=391 for N=100K)
#define NWG 256               // edge slices / scatter workgroups
#define CAP 6144              // LDS reorder buffer (mean bucket ~4096 edges)
#define NPB 128               // nodes per aggregate block (work-steal pool)

typedef _Float16 half8 __attribute__((ext_vector_type(8)));
typedef float f32x4 __attribute__((ext_vector_type(4)));

__device__ __forceinline__ void h8_to_f(const uint4& u, float* f) {
  const __half2* hp = (const __half2*)&u;
#pragma unroll
  for (int i = 0; i < 4; ++i) {
    float2 t = __half22float2(hp[i]);
    f[2 * i] = t.x;
    f[2 * i + 1] = t.y;
  }
}

// inclusive scan of v across a 256-thread block; wsums is __shared__ int[4]
__device__ __forceinline__ int block_scan256(int v, int* wsums) {
  const int lane = threadIdx.x & 63;
  const int wid = threadIdx.x >> 6;
  int x = v;
#pragma unroll
  for (int d = 1; d < 64; d <<= 1) {
    int y = __shfl_up(x, d);
    if (lane >= d) x += y;
  }
  if (lane == 63) wsums[wid] = x;
  __syncthreads();
  int off = 0;
#pragma unroll
  for (int j = 0; j < 4; ++j)
    if (j < wid) off += wsums[j];
  return off + x;
}

// Pass 1: per-wg LDS histogram of its edge slice -> counts[wg*NBPAD + b]
__global__ __launch_bounds__(256) void wg_count(const int* __restrict__ dst,
                                                int* __restrict__ counts,
                                                int E, int nb, int slice) {
  __shared__ int lh[NBPAD];
  const int w = blockIdx.x;
  for (int i = threadIdx.x; i < nb; i += 256) lh[i] = 0;
  __syncthreads();
  const int e0 = w * slice;
  const int e1 = min(e0 + slice, E);
  for (int e = e0 + threadIdx.x; e < e1; e += 256)
    atomicAdd(&lh[dst[e] >> BSHIFT], 1);
  __syncthreads();
  for (int i = threadIdx.x; i < nb; i += 256) counts[(size_t)w * NBPAD + i] = lh[i];
}

// Pass 2: single block — per-bucket totals + exclusive scan -> bstart[0..nb]
__global__ __launch_bounds__(1024) void scan_buckets(const int* __restrict__ counts,
                                                     int* __restrict__ bstart,
                                                     int* __restrict__ row_start,
                                                     int nb, int n, int E) {
  __shared__ int wsum[16];
  const int tid = threadIdx.x;
  const int lane = tid & 63;
  const int wid = tid >> 6;
  int v = 0;
  if (tid < nb) {
#pragma unroll 4
    for (int i = 0; i < NWG; ++i) v += counts[(size_t)i * NBPAD + tid];
  }
  int x = v;
#pragma unroll
  for (int d = 1; d < 64; d <<= 1) {
    int y = __shfl_up(x, d);
    if (lane >= d) x += y;
  }
  if (lane == 63) wsum[wid] = x;
  __syncthreads();
  if (wid == 0) {
    int w = (lane < 16) ? wsum[lane] : 0;
#pragma unroll
    for (int d = 1; d < 16; d <<= 1) {
      int y = __shfl_up(w, d);
      if (lane >= d) w += y;
    }
    if (lane < 16) wsum[lane] = w;
  }
  __syncthreads();
  int boff = (wid > 0) ? wsum[wid - 1] : 0;
  int incl = boff + x;
  if (tid < nb) {
    bstart[tid] = incl - v;
    if (tid == nb - 1) bstart[nb] = incl;
  }
  if (tid == 0) row_start[n] = E;
}

// Pass 3: one block per bucket — exclusive scan across wgs -> cur[wg][b]
__global__ __launch_bounds__(256) void cell_scan(const int* __restrict__ counts,
                                                 const int* __restrict__ bstart,
                                                 int* __restrict__ cur, int nb) {
  __shared__ int wsums[4];
  const int b = blockIdx.x;
  const int tid = threadIdx.x;
  int v = counts[(size_t)tid * NBPAD + b];
  int incl = block_scan256(v, wsums);
  cur[(size_t)tid * NBPAD + b] = bstart[b] + incl - v;
}

// Pass 4: scatter with LDS cursors — each (wg,bucket) range written by one wg
__global__ __launch_bounds__(256) void wg_scatter(const int* __restrict__ src,
                                                  const int* __restrict__ dst,
                                                  const int* __restrict__ cur,
                                                  unsigned* __restrict__ staging,
                                                  int E, int nb, int slice) {
  __shared__ int lc[NBPAD];
  const int w = blockIdx.x;
  for (int i = threadIdx.x; i < nb; i += 256) lc[i] = cur[(size_t)w * NBPAD + i];
  __syncthreads();
  const int e0 = w * slice;
  const int e1 = min(e0 + slice, E);
  for (int e = e0 + threadIdx.x; e < e1; e += 256) {
    int d = dst[e];
    int p = atomicAdd(&lc[d >> BSHIFT], 1);
    staging[p] = ((unsigned)(d & 255) << 24) | (unsigned)src[e];
  }
}

// Pass 5: per-bucket finalize — row_start, dinv, coalesced csr_src
__global__ __launch_bounds__(256) void bucket_finalize(const unsigned* __restrict__ staging,
                                                       const int* __restrict__ bstart,
                                                       int* __restrict__ csr_src,
                                                       int* __restrict__ row_start,
                                                       float* __restrict__ dinv, int n) {
  __shared__ int lcnt[256];
  __shared__ int lcur[256];
  __shared__ int wsums[4];
  __shared__ int lbuf[CAP];
  const int b = blockIdx.x;
  const int tid = threadIdx.x;
  const int n0 = b << BSHIFT;
  const int s0 = bstart[b];
  const int cnt = bstart[b + 1] - s0;

  lcnt[tid] = 0;
  __syncthreads();
  for (int i = tid; i < cnt; i += 256)
    atomicAdd(&lcnt[staging[s0 + i] >> 24], 1);
  __syncthreads();

  const int v = lcnt[tid];
  const int incl = block_scan256(v, wsums);
  const int excl = incl - v;
  lcur[tid] = excl;
  const int node = n0 + tid;
  if (node < n) {
    row_start[node] = s0 + excl;
    dinv[node] = rsqrtf((float)v + 1.0f);
  }
  __syncthreads();

  for (int i = tid; i < cnt; i += 256) {
    unsigned p = staging[s0 + i];
    int pos = atomicAdd(&lcur[p >> 24], 1);
    int s = (int)(p & 0xFFFFFFu);
    if (pos < CAP) lbuf[pos] = s;
    else csr_src[s0 + pos] = s;  // overflow fallback (statistically never)
  }
  __syncthreads();
  const int lim = cnt < CAP ? cnt : CAP;
  for (int i = tid; i < lim; i += 256) csr_src[s0 + i] = lbuf[i];
}

__global__ __launch_bounds__(256) void make_pack(const int* __restrict__ csr_src,
                                                 const float* __restrict__ dinv,
                                                 int2* __restrict__ pack, int E) {
  int e = blockIdx.x * 256 + threadIdx.x;
  if (e < E) {
    int s = csr_src[e];
    pack[e] = make_int2(s, __float_as_int(dinv[s]));
  }
}

// Pack W[128][M] fp32 -> Wp fp16 fragment order:
// Wp[((t*M + c)*4 + g)*8 + j] = W[t*32 + g*8 + j][c]
template <int M>
__global__ __launch_bounds__(256) void pack_w(const float* __restrict__ W,
                                              _Float16* __restrict__ Wp) {
  int e = blockIdx.x * 256 + threadIdx.x;
  if (e < 128 * M) {
    int k = e / M, c = e % M;
    int t = k >> 5, g = (k >> 3) & 3, j = k & 7;
    Wp[(((size_t)t * M + c) * 4 + g) * 8 + j] = (_Float16)W[e];
  }
}

// H[N,M] = X[N,128] @ W[128,M] via v_mfma_f32_16x16x32_f16. Zero LDS.
template <int M, bool HIN>
__global__ __launch_bounds__(256) void gemm_mfma(const void* __restrict__ Xp,
                                                 const _Float16* __restrict__ Wp,
                                                 _Float16* __restrict__ H, int N) {
  constexpr int CT = M / 16;
  const int wave = threadIdx.x >> 6;
  const int lane = threadIdx.x & 63;
  const int row0 = (blockIdx.x * 4 + wave) * 16;
  if (row0 >= N) return;
  const int r = lane & 15;
  const int g = lane >> 4;
  int row = row0 + r;
  if (row >= N) row = N - 1;

  f32x4 acc[CT];
#pragma unroll
  for (int c = 0; c < CT; ++c) acc[c] = (f32x4){0.f, 0.f, 0.f, 0.f};

#pragma unroll
  for (int t = 0; t < 4; ++t) {
    half8 a;
    if constexpr (HIN) {
      a = *(const half8*)((const _Float16*)Xp + (size_t)row * 128 + t * 32 + g * 8);
    } else {
      const float* xp = (const float*)Xp + (size_t)row * 128 + t * 32 + g * 8;
      float4 x0 = *(const float4*)xp;
      float4 x1 = *(const float4*)(xp + 4);
      a[0] = (_Float16)x0.x; a[1] = (_Float16)x0.y;
      a[2] = (_Float16)x0.z; a[3] = (_Float16)x0.w;
      a[4] = (_Float16)x1.x; a[5] = (_Float16)x1.y;
      a[6] = (_Float16)x1.z; a[7] = (_Float16)x1.w;
    }
#pragma unroll
    for (int c = 0; c < CT; ++c) {
      half8 b = *(const half8*)(Wp + (((size_t)t * M + c * 16 + r) * 4 + g) * 8);
      acc[c] = __builtin_amdgcn_mfma_f32_16x16x32_f16(a, b, acc[c], 0, 0, 0);
    }
  }

#pragma unroll
  for (int c = 0; c < CT; ++c) {
#pragma unroll
    for (int i = 0; i < 4; ++i) {
      int rr = row0 + 4 * g + i;
      if (rr < N) H[(size_t)rr * M + c * 16 + r] = (_Float16)acc[c][i];
    }
  }
}

// out[node] = di*( sum_e w_e*h[src_e] + di*h[node] ) + bias (+softmax).
// 8-lane groups (32 per block); lane owns F/8 contiguous features.
// Blocks own NPB consecutive nodes; groups work-steal from an LDS queue.
// ONE atomic per group (lane 0), broadcast via __shfl(...,0,8).
template <int F, bool SM, bool OUTHALF, int UNROLL>
__global__ __launch_bounds__(256) void aggregate(const __half* __restrict__ h,
                                                 const int* __restrict__ row_start,
                                                 const int2* __restrict__ pack,
                                                 const float* __restrict__ dinv,
                                                 const float* __restrict__ bias,
                                                 void* __restrict__ out, int n) {
  constexpr int FPL = F / 8;   // features per lane: 16 (F=128) / 8 (F=64)
  constexpr int V = FPL / 8;   // uint4 row-loads per lane: 2 / 1
  __shared__ int qpos;
  const int base = blockIdx.x * NPB;
  const int lane = threadIdx.x & 7;
  if (threadIdx.x == 0) qpos = 0;
  __syncthreads();

  const uint4* hv = (const uint4*)h;  // row stride F/8 uint4

  for (;;) {
    int idx = 0;
    if (lane == 0) idx = atomicAdd(&qpos, 1);   // one claim per GROUP
    idx = __shfl(idx, 0, 8);                    // broadcast within 8-lane group
    if (idx >= NPB) break;
    const int node = base + idx;
    if (node >= n) break;

    const float di = dinv[node];
    float acc[FPL];
    {
      uint4 su[V];
#pragma unroll
      for (int v = 0; v < V; ++v)
        su[v] = hv[(size_t)node * (F / 8) + lane * V + v];
#pragma unroll
      for (int v = 0; v < V; ++v) {
        float sf[8];
        h8_to_f(su[v], sf);
#pragma unroll
        for (int i = 0; i < 8; ++i) acc[v * 8 + i] = di * sf[i];
      }
    }

    int e = row_start[node];
    const int e1 = row_start[node + 1];
    for (; e + UNROLL <= e1; e += UNROLL) {
      int2 p[UNROLL];
      uint4 r[UNROLL][V];
#pragma unroll
      for (int j = 0; j < UNROLL; ++j) p[j] = pack[e + j];
#pragma unroll
      for (int j = 0; j < UNROLL; ++j)
#pragma unroll
        for (int v = 0; v < V; ++v)
          r[j][v] = hv[(size_t)p[j].x * (F / 8) + lane * V + v];
#pragma unroll
      for (int j = 0; j < UNROLL; ++j) {
        const float w = __int_as_float(p[j].y);
#pragma unroll
        for (int v = 0; v < V; ++v) {
          float vf[8];
          h8_to_f(r[j][v], vf);
#pragma unroll
          for (int i = 0; i < 8; ++i) acc[v * 8 + i] = fmaf(w, vf[i], acc[v * 8 + i]);
        }
      }
    }
    if constexpr (UNROLL > 4) {
      for (; e + 4 <= e1; e += 4) {
        int2 p[4];
        uint4 r[4][V];
#pragma unroll
        for (int j = 0; j < 4; ++j) p[j] = pack[e + j];
#pragma unroll
        for (int j = 0; j < 4; ++j)
#pragma unroll
          for (int v = 0; v < V; ++v)
            r[j][v] = hv[(size_t)p[j].x * (F / 8) + lane * V + v];
#pragma unroll
        for (int j = 0; j < 4; ++j) {
          const float w = __int_as_float(p[j].y);
#pragma unroll
          for (int v = 0; v < V; ++v) {
            float vf[8];
            h8_to_f(r[j][v], vf);
#pragma unroll
            for (int i = 0; i < 8; ++i) acc[v * 8 + i] = fmaf(w, vf[i], acc[v * 8 + i]);
          }
        }
      }
    }
    for (; e < e1; ++e) {
      int2 p = pack[e];
      const float w = __int_as_float(p.y);
#pragma unroll
      for (int v = 0; v < V; ++v) {
        uint4 r = hv[(size_t)p.x * (F / 8) + lane * V + v];
        float vf[8];
        h8_to_f(r, vf);
#pragma unroll
        for (int i = 0; i < 8; ++i) acc[v * 8 + i] = fmaf(w, vf[i], acc[v * 8 + i]);
      }
    }

    {
      const float4* bv = (const float4*)bias;
#pragma unroll
      for (int q = 0; q < FPL / 4; ++q) {
        float4 b = bv[lane * (FPL / 4) + q];
        acc[q * 4 + 0] = fmaf(di, acc[q * 4 + 0], b.x);
        acc[q * 4 + 1] = fmaf(di, acc[q * 4 + 1], b.y);
        acc[q * 4 + 2] = fmaf(di, acc[q * 4 + 2], b.z);
        acc[q * 4 + 3] = fmaf(di, acc[q * 4 + 3], b.w);
      }
    }

    if constexpr (SM) {
      float m = acc[0];
#pragma unroll
      for (int i = 1; i < FPL; ++i) m = fmaxf(m, acc[i]);
#pragma unroll
      for (int off = 4; off >= 1; off >>= 1) m = fmaxf(m, __shfl_xor(m, off));
      float ex[FPL], ssum = 0.f;
#pragma unroll
      for (int i = 0; i < FPL; ++i) {
        ex[i] = __expf(acc[i] - m);
        ssum += ex[i];
      }
#pragma unroll
      for (int off = 4; off >= 1; off >>= 1) ssum += __shfl_xor(ssum, off);
      const float rs = 1.0f / ssum;
#pragma unroll
      for (int i = 0; i < FPL; ++i) acc[i] = ex[i] * rs;
    }

    if constexpr (OUTHALF) {
#pragma unroll
      for (int v = 0; v < V; ++v) {
        union { __half2 h2[4]; uint4 u; } cv;
#pragma unroll
        for (int i = 0; i < 4; ++i)
          cv.h2[i] = __floats2half2_rn(acc[v * 8 + 2 * i], acc[v * 8 + 2 * i + 1]);
        ((uint4*)out)[(size_t)node * (F / 8) + lane * V + v] = cv.u;
      }
    } else {
      float4* ov = (float4*)out;
#pragma unroll
      for (int q = 0; q < FPL / 4; ++q)
        ov[(size_t)node * (F / 4) + lane * (FPL / 4) + q] =
            make_float4(acc[q * 4 + 0], acc[q * 4 + 1], acc[q * 4 + 2], acc[q * 4 + 3]);
    }
  }
}

extern "C" void kernel_launch(void* const* d_in, const int* in_sizes, int n_in,
                              void* d_out, int out_size, void* d_ws, size_t ws_size,
                              hipStream_t stream) {
  const float* x  = (const float*)d_in[0];
  const float* W1 = (const float*)d_in[1];
  const float* b1 = (const float*)d_in[2];
  const float* W2 = (const float*)d_in[3];
  const float* b2 = (const float*)d_in[4];
  const int*   ei = (const int*)d_in[5];

  const int N = in_sizes[0] / 128;
  const int E = in_sizes[5] / 2;
  const int NB = (N + 255) >> BSHIFT;          // 391 for N=100K (<= NBPAD)
  const int SLICE = (E + NWG - 1) / NWG;
  const int* srcp = ei;
  const int* dstp = ei + E;

  auto align256 = [](size_t v) { return (v + 255) & ~(size_t)255; };
  char* ws = (char*)d_ws;
  size_t o_dinv   = 0;
  size_t o_rs     = align256(o_dinv + (size_t)N * 4);
  size_t o_cnts   = align256(o_rs + (size_t)(N + 1) * 4);
  size_t o_cur    = align256(o_cnts + (size_t)NWG * NBPAD * 4);
  size_t o_bstart = align256(o_cur + (size_t)NWG * NBPAD * 4);
  size_t o_wp1    = align256(o_bstart + (size_t)(NBPAD + 1) * 4);
  size_t o_wp2    = align256(o_wp1 + (size_t)128 * 128 * 2);
  size_t o_stg    = align256(o_wp2 + (size_t)128 * 64 * 2);
  size_t o_csr    = align256(o_stg + (size_t)E * 4);
  size_t o_pack   = align256(o_csr + (size_t)E * 4);
  size_t o_h1     = align256(o_pack + (size_t)E * 8);
  size_t o_s      = align256(o_h1 + (size_t)N * 128 * 2);

  float*    dinv     = (float*)(ws + o_dinv);
  int*      rowstart = (int*)(ws + o_rs);
  int*      counts   = (int*)(ws + o_cnts);
  int*      cur      = (int*)(ws + o_cur);
  int*      bstart   = (int*)(ws + o_bstart);
  _Float16* wp1      = (_Float16*)(ws + o_wp1);
  _Float16* wp2      = (_Float16*)(ws + o_wp2);
  unsigned* staging  = (unsigned*)(ws + o_stg);
  int*      csr_src  = (int*)(ws + o_csr);
  int2*     pack     = (int2*)(ws + o_pack);
  _Float16* h1       = (_Float16*)(ws + o_h1);  // [N,128] fp16; reused as h2 [N,64]
  _Float16* sbuf     = (_Float16*)(ws + o_s);   // [N,128] fp16 softmax output

  // CSR build — no global atomics anywhere
  wg_count<<<NWG, 256, 0, stream>>>(dstp, counts, E, NB, SLICE);
  scan_buckets<<<1, 1024, 0, stream>>>(counts, bstart, rowstart, NB, N, E);
  cell_scan<<<NB, 256, 0, stream>>>(counts, bstart, cur, NB);
  wg_scatter<<<NWG, 256, 0, stream>>>(srcp, dstp, cur, staging, E, NB, SLICE);
  bucket_finalize<<<NB, 256, 0, stream>>>(staging, bstart, csr_src, rowstart, dinv, N);
  make_pack<<<(E + 255) / 256, 256, 0, stream>>>(csr_src, dinv, pack, E);

  // Weight packing (tiny)
  pack_w<128><<<(128 * 128 + 255) / 256, 256, 0, stream>>>(W1, wp1);
  pack_w<64><<<(128 * 64 + 255) / 256, 256, 0, stream>>>(W2, wp2);

  const int aggGrid = (N + NPB - 1) / NPB;
  // Layer 1
  gemm_mfma<128, false><<<(N + 63) / 64, 256, 0, stream>>>(x, wp1, h1, N);
  aggregate<128, true, true, 4><<<aggGrid, 256, 0, stream>>>(
      (const __half*)h1, rowstart, pack, dinv, b1, sbuf, N);
  // Layer 2
  gemm_mfma<64, true><<<(N + 63) / 64, 256, 0, stream>>>(sbuf, wp2, h1, N);
  aggregate<64, false, false, 8><<<aggGrid, 256, 0, stream>>>(
      (const __half*)h1, rowstart, pack, dinv, b2, d_out, N);
}